// Round 5
// baseline (304.464 us; speedup 1.0000x reference)
//
#include <hip/hip_runtime.h>
#include <float.h>
#include <math.h>

// Problem constants: query (8,512,64,64) f32, keys (2000,512) f32
constexpr int D_  = 512;
constexpr int HW_ = 4096;           // 64*64
constexpr int N_  = 32768;          // B*HW
constexpr int M_  = 2000;
constexpr int MP_ = 2048;           // padded key count

typedef _Float16 half8 __attribute__((ext_vector_type(8)));
typedef float    f32x4 __attribute__((ext_vector_type(4)));

// async global->LDS, 16B per lane. LDS dest = base (wave-uniform) + lane*16.
__device__ inline void async16(void* lds, const void* g) {
    __builtin_amdgcn_global_load_lds(
        (const __attribute__((address_space(1))) unsigned int*)g,
        (__attribute__((address_space(3))) unsigned int*)lds, 16, 0, 0);
}

// ---------------- kernel 1: fused per-pixel rnorm + fp16 A-fragment swizzle ----------------
// qsw holds NORMALIZED q-hat. Downstream score is s = kn - 2*acc (acc already has rnorm).
// qsw[pb][kb][lane][j]: lane L holds A[m = pb*16 + (L&15)][k = kb*32 + (L>>4)*8 + j]
__global__ __launch_bounds__(256) void k_prep(const float* __restrict__ q,
                                              float* __restrict__ rnorm,
                                              _Float16* __restrict__ qsw) {
    __shared__ float tile[64][65];
    __shared__ float part[64][5];
    __shared__ float rns[64];
    int t = threadIdx.x;
    int pl = t & 63, cg = t >> 6;
    int p0 = blockIdx.x * 64;                    // 64 | 4096 -> single batch per block
    const float* base = q + (size_t)(p0 / HW_) * (D_ * HW_) + (p0 % HW_);

    float s = 0.f;
    for (int c = cg * 128; c < cg * 128 + 128; ++c) {
        float v = base[(size_t)c * HW_ + pl];    // coalesced along hw
        s += v * v;
    }
    part[pl][cg] = s;
    __syncthreads();
    if (t < 64) {
        float ss = part[t][0] + part[t][1] + part[t][2] + part[t][3];
        float rv = 1.0f / fmaxf(sqrtf(ss), 1e-12f);   // matches F.normalize eps
        rns[t] = rv;
        rnorm[p0 + t] = rv;
    }

    int pb0 = blockIdx.x * 4;
    for (int ct = 0; ct < 8; ++ct) {
        __syncthreads();                         // tile free (prev readers done) + rns ready
#pragma unroll
        for (int i = 0; i < 4; ++i) {
            int sl = t + 256 * i;                // 1024 float4 slots: 64 ch-rows x 16
            int row = sl >> 4, p4 = (sl & 15) * 4;
            float4 v = *(const float4*)(base + (size_t)(ct * 64 + row) * HW_ + p4);
            tile[row][p4 + 0] = v.x; tile[row][p4 + 1] = v.y;
            tile[row][p4 + 2] = v.z; tile[row][p4 + 3] = v.w;
        }
        __syncthreads();
#pragma unroll
        for (int i = 0; i < 2; ++i) {
            int f = t + 256 * i;                 // 512 fragments: 8 tiles x 64 lanes
            int ti = f >> 6, L = f & 63;
            int pbi = ti & 3, kbi = ti >> 2;
            int plx = pbi * 16 + (L & 15);
            int cl = kbi * 32 + ((L >> 4) * 8);
            float rv = rns[plx];
            half8 hv;
#pragma unroll
            for (int j = 0; j < 8; ++j) hv[j] = (_Float16)(tile[cl + j][plx] * rv);
            size_t off = (((size_t)(pb0 + pbi) * 16 + (ct * 2 + kbi)) * 64 + L) * 8;
            *(half8*)(qsw + off) = hv;
        }
    }
}

// ---------------- kernel 2: |k|^2 (FLT_MAX for padding) ----------------
__global__ __launch_bounds__(256) void k_kn(const float* __restrict__ keys,
                                            float* __restrict__ kn) {
    int wave = threadIdx.x >> 6;
    int lane = threadIdx.x & 63;
    int m = blockIdx.x * 4 + wave;
    float s = 0.f;
    if (m < M_) {
        const float4* row = (const float4*)(keys + (size_t)m * D_);
        for (int j = lane; j < D_ / 4; j += 64) {
            float4 v = row[j];
            s += v.x * v.x + v.y * v.y + v.z * v.z + v.w * v.w;
        }
    }
    for (int off = 32; off; off >>= 1) s += __shfl_down(s, off, 64);
    if (lane == 0) kn[m] = (m < M_) ? s : FLT_MAX;
}

// ---------------- kernel 3: keys -> fp16, MFMA B-fragment order ----------------
// ksw[nb][kb][lane][j]: lane L holds B[k][n=nb*16+(L&15)] = keys[n][kb*32+(L>>4)*8+j]
__global__ __launch_bounds__(256) void k_ksw(const float* __restrict__ keys,
                                             _Float16* __restrict__ ksw) {
    int f = blockIdx.x * 256 + threadIdx.x;      // 131072 fragments
    int nb = f >> 10, rest = f & 1023;
    int kb = rest >> 6, L = rest & 63;
    int m = nb * 16 + (L & 15);
    int c = kb * 32 + ((L >> 4) * 8);
    half8 hv;
    if (m < M_) {
        float4 v0 = *(const float4*)(keys + (size_t)m * D_ + c);
        float4 v1 = *(const float4*)(keys + (size_t)m * D_ + c + 4);
        hv[0] = (_Float16)v0.x; hv[1] = (_Float16)v0.y;
        hv[2] = (_Float16)v0.z; hv[3] = (_Float16)v0.w;
        hv[4] = (_Float16)v1.x; hv[5] = (_Float16)v1.y;
        hv[6] = (_Float16)v1.z; hv[7] = (_Float16)v1.w;
    } else {
#pragma unroll
        for (int j = 0; j < 8; ++j) hv[j] = (_Float16)0.f;
    }
    *(half8*)(ksw + (size_t)f * 8) = hv;
}

// merge top-2 list (t1,j1,t2,j2) into (s1,i1,s2,i2); both sorted; idx tie-break.
__device__ inline void merge2(float& s1, unsigned& i1, float& s2, unsigned& i2,
                              float t1, unsigned j1, float t2, unsigned j2) {
    if (t1 < s1 || (t1 == s1 && j1 < i1)) {
        float os = s1; unsigned oi = i1;
        s1 = t1; i1 = j1;
        if (os < t2 || (os == t2 && oi < j2)) { s2 = os; i2 = oi; }
        else { s2 = t2; i2 = j2; }
    } else {
        if (t1 < s2 || (t1 == s2 && j1 < i2)) { s2 = t1; i2 = j1; }
    }
}

// ---------------- kernel 4: MFMA score GEMM, chunk loop + packed running top-2 ----------------
// grid (N/128, 4) = 1024 blocks -> 4 blocks/CU (VGPR 128 = 4 waves/SIMD, LDS 32KB*4 < 160KB).
// Block: 128 pixels x 512 keys (4 chunks of 128), 4 waves in 2x2.
// acc = q-hat . k -> s = kn - 2*acc, always positive -> float bits compare as unsigned.
// Pack thread-local key id (4 bits) into low mantissa: top-2 fold = 3 int min/max;
// trunc 16 ulp ~ 1e-3 ~ fp16 GEMM noise (both absorbed by the exact fp32 rescue).
__global__ __launch_bounds__(256, 4) void k_mfma(const _Float16* __restrict__ qsw,
                                                 const _Float16* __restrict__ ksw,
                                                 const float* __restrict__ kn,
                                                 float4* __restrict__ best) {
    __shared__ _Float16 As[16 * 512];            // 16 KiB: 16 tiles (kbi*8+pbi) x 1024B
    __shared__ _Float16 Bs[16 * 512];            // 16 KiB
    int t = threadIdx.x;
    int lane = t & 63;
    int w = __builtin_amdgcn_readfirstlane(t >> 6);
    int wr = w >> 1, wc = w & 1;
    int colk = lane & 15, quad = lane >> 4;
    int p0 = blockIdx.x * 128;
    int yb = blockIdx.y;                         // key quarter: yb*512
    int pb0 = p0 >> 4;

    unsigned pk1[16], pk2[16];
#pragma unroll
    for (int i = 0; i < 16; ++i) { pk1[i] = 0xFFFFFFFFu; pk2[i] = 0xFFFFFFFFu; }

    for (int ch = 0; ch < 4; ++ch) {
        int m0 = yb * 512 + ch * 128;
        int nb0 = m0 >> 4;
        f32x4 acc[4][4];
#pragma unroll
        for (int pi = 0; pi < 4; ++pi)
#pragma unroll
            for (int ni = 0; ni < 4; ++ni) acc[pi][ni] = (f32x4){0.f, 0.f, 0.f, 0.f};

        for (int dc = 0; dc < 8; ++dc) {         // K-steps of 64
            int kb0 = dc * 2;
            __syncthreads();                     // prior readers done
#pragma unroll
            for (int i = 0; i < 4; ++i) {        // wave w stages tiles w*4..w*4+3
                int ti = w * 4 + i;
                int kbi = ti >> 3, pbi = ti & 7; // pbi doubles as nbi for B
                async16(&As[ti * 512],
                        qsw + (((size_t)(pb0 + pbi) * 16 + (kb0 + kbi)) * 64 + lane) * 8);
                async16(&Bs[ti * 512],
                        ksw + (((size_t)(nb0 + pbi) * 16 + (kb0 + kbi)) * 64 + lane) * 8);
            }
            __syncthreads();                     // staging drained
#pragma unroll
            for (int kbi = 0; kbi < 2; ++kbi) {
                half8 a[4], b[4];
#pragma unroll
                for (int pi = 0; pi < 4; ++pi)
                    a[pi] = *(const half8*)&As[(kbi * 8 + wr * 4 + pi) * 512 + lane * 8];
#pragma unroll
                for (int ni = 0; ni < 4; ++ni)
                    b[ni] = *(const half8*)&Bs[(kbi * 8 + wc * 4 + ni) * 512 + lane * 8];
#pragma unroll
                for (int pi = 0; pi < 4; ++pi)
#pragma unroll
                    for (int ni = 0; ni < 4; ++ni)
                        acc[pi][ni] = __builtin_amdgcn_mfma_f32_16x16x32_f16(
                            a[pi], b[ni], acc[pi][ni], 0, 0, 0);
            }
        }
        // fold this chunk's 4 scores/row into the packed running top-2
        float knv[4];
#pragma unroll
        for (int ni = 0; ni < 4; ++ni) knv[ni] = kn[m0 + wc * 64 + ni * 16 + colk];
#pragma unroll
        for (int pi = 0; pi < 4; ++pi) {
#pragma unroll
            for (int r = 0; r < 4; ++r) {
                int si = pi * 4 + r;
#pragma unroll
                for (int ni = 0; ni < 4; ++ni) {
                    float sc = fmaf(-2.0f, acc[pi][ni][r], knv[ni]);
                    unsigned p = (__float_as_uint(sc) & ~15u) | (unsigned)(ch * 4 + ni);
                    unsigned hi = pk1[si] > p ? pk1[si] : p;   // max
                    pk1[si] = pk1[si] < p ? pk1[si] : p;       // min
                    pk2[si] = pk2[si] < hi ? pk2[si] : hi;     // min
                }
            }
        }
    }

    // ---- once-per-block epilogue: unpack, butterfly over 16 colk lanes, LDS wc-merge ----
    __syncthreads();
    float4* red = (float4*)(void*)As;            // [128 pixels][2 waves], 4 KiB
#pragma unroll
    for (int pi = 0; pi < 4; ++pi) {
#pragma unroll
        for (int r = 0; r < 4; ++r) {
            int si = pi * 4 + r;
            int pix = wr * 64 + pi * 16 + quad * 4 + r;
            unsigned P1 = pk1[si], P2 = pk2[si];
            float s1 = __uint_as_float(P1 & ~15u);
            float s2 = __uint_as_float(P2 & ~15u);
            unsigned l1 = P1 & 15u, l2 = P2 & 15u;
            unsigned i1 = (unsigned)(yb * 512) + (l1 >> 2) * 128 + wc * 64 + (l1 & 3) * 16 + colk;
            unsigned i2 = (unsigned)(yb * 512) + (l2 >> 2) * 128 + wc * 64 + (l2 & 3) * 16 + colk;
#pragma unroll
            for (int mask = 1; mask < 16; mask <<= 1) {
                float t1 = __shfl_xor(s1, mask, 64);
                float t2 = __shfl_xor(s2, mask, 64);
                unsigned j1 = (unsigned)__shfl_xor((int)i1, mask, 64);
                unsigned j2 = (unsigned)__shfl_xor((int)i2, mask, 64);
                merge2(s1, i1, s2, i2, t1, j1, t2, j2);
            }
            if (colk == 0)
                red[pix * 2 + wc] = make_float4(s1, __uint_as_float(i1),
                                                s2, __uint_as_float(i2));
        }
    }
    __syncthreads();
    if (t < 128) {
        float4 e0 = red[t * 2 + 0];
        float4 e1 = red[t * 2 + 1];
        float s1 = e0.x, s2 = e0.z;
        unsigned i1 = __float_as_uint(e0.y), i2 = __float_as_uint(e0.w);
        merge2(s1, i1, s2, i2, e1.x, __float_as_uint(e1.y), e1.z, __float_as_uint(e1.w));
        best[(size_t)yb * N_ + p0 + t] =
            make_float4(s1, __uint_as_float(i1), s2, __uint_as_float(i2));
    }
}

// ---------------- kernel 5: merge 4 quarters -> top-2, exact fp32 rescue + heatmap ----------------
// Block = 64 pixels x 4 c-groups (256 thr); 512 blocks -> 2 blocks/CU, 8 waves/CU.
__global__ __launch_bounds__(256) void k_heat(
    const float* __restrict__ q, const float* __restrict__ keys,
    const float* __restrict__ kn, const float* __restrict__ rnorm,
    const float4* __restrict__ best, float* __restrict__ out)
{
    __shared__ float4 part[64][5];               // (dot0,dot1,hh0,hh1) x 4 cg, +1 pad
    int t = threadIdx.x;
    int pl = t & 63, cg = t >> 6;
    int p0 = blockIdx.x * 64;
    int p = p0 + pl;
    const float* qb = q + (size_t)(p / HW_) * (D_ * HW_) + (p % HW_);

    // merge the 4 per-quarter top-2 lists (done redundantly in each cg thread)
    float4 e0 = best[p];
    float s1 = e0.x, s2 = e0.z;
    unsigned i1 = __float_as_uint(e0.y), i2 = __float_as_uint(e0.w);
#pragma unroll
    for (int yb = 1; yb < 4; ++yb) {
        float4 e = best[(size_t)yb * N_ + p];
        merge2(s1, i1, s2, i2, e.x, __float_as_uint(e.y), e.z, __float_as_uint(e.w));
    }

    float rn = rnorm[p];
    const float* kp0 = keys + (size_t)i1 * D_;
    const float* kp1 = keys + (size_t)i2 * D_;
    float dot0 = 0.f, dot1 = 0.f, hh0 = 0.f, hh1 = 0.f;
    for (int c = cg * 128; c < cg * 128 + 128; c += 4) {
        float qv[4];
#pragma unroll
        for (int j = 0; j < 4; ++j) qv[j] = qb[(size_t)(c + j) * HW_] * rn;  // coalesced
        float4 kv0 = *(const float4*)(kp0 + c);
        float4 kv1 = *(const float4*)(kp1 + c);
        dot0 += qv[0] * kv0.x + qv[1] * kv0.y + qv[2] * kv0.z + qv[3] * kv0.w;
        dot1 += qv[0] * kv1.x + qv[1] * kv1.y + qv[2] * kv1.z + qv[3] * kv1.w;
        float a0 = qv[0] - kv0.x, a1 = qv[1] - kv0.y, a2 = qv[2] - kv0.z, a3 = qv[3] - kv0.w;
        float b0 = qv[0] - kv1.x, b1 = qv[1] - kv1.y, b2 = qv[2] - kv1.z, b3 = qv[3] - kv1.w;
        float A0 = a0 * a0, A1 = a1 * a1, A2 = a2 * a2, A3 = a3 * a3;
        float B0 = b0 * b0, B1 = b1 * b1, B2 = b2 * b2, B3 = b3 * b3;
        hh0 += A0 * A0 + A1 * A1 + A2 * A2 + A3 * A3;
        hh1 += B0 * B0 + B1 * B1 + B2 * B2 + B3 * B3;
    }
    part[pl][cg] = make_float4(dot0, dot1, hh0, hh1);
    __syncthreads();
    if (t < 64) {                                // cg==0 thread for pixel t: has i1,i2
        float4 a = part[t][0], b = part[t][1], c4 = part[t][2], d = part[t][3];
        float dA = a.x + b.x + c4.x + d.x;
        float dB = a.y + b.y + c4.y + d.y;
        float hA = a.z + b.z + c4.z + d.z;
        float hB = a.w + b.w + c4.w + d.w;
        float sA = kn[i1] - 2.0f * dA;
        float sB = kn[i2] - 2.0f * dB;
        // argmin semantics: smaller exact score wins; tie -> smaller index
        bool takeB = (sB < sA) || (sB == sA && i2 < i1);
        out[p0 + t] = takeB ? hB : hA;
    }
}

extern "C" void kernel_launch(void* const* d_in, const int* in_sizes, int n_in,
                              void* d_out, int out_size, void* d_ws, size_t ws_size,
                              hipStream_t stream) {
    const float* query = (const float*)d_in[0];   // (8,512,64,64) f32
    const float* keys  = (const float*)d_in[1];   // (2000,512) f32
    float* out = (float*)d_out;                   // 32768 f32

    // workspace layout (~38 MB):
    char* ws = (char*)d_ws;
    _Float16* qsw   = (_Float16*)ws;                                 // N*D fp16  = 33.5 MB
    _Float16* ksw   = (_Float16*)(ws + (size_t)N_ * D_ * 2);         // MP*D fp16 = 2 MB
    float*    rnorm = (float*)(ws + (size_t)N_ * D_ * 2 + (size_t)MP_ * D_ * 2);
    float*    kn    = rnorm + N_;
    float4*   best  = (float4*)(kn + MP_);                           // 4*N float4 = 2 MB

    k_kn  <<<MP_ / 4,             256, 0, stream>>>(keys, kn);
    k_ksw <<<MP_ * D_ / 8 / 256,  256, 0, stream>>>(keys, ksw);
    k_prep<<<N_ / 64,             256, 0, stream>>>(query, rnorm, qsw);
    k_mfma<<<dim3(N_ / 128, 4),   256, 0, stream>>>(qsw, ksw, kn, best);
    k_heat<<<N_ / 64,             256, 0, stream>>>(query, keys, kn, rnorm, best, out);
}

// Round 7
// 217.767 us; speedup vs baseline: 1.3981x; 1.3981x over previous
//
#include <hip/hip_runtime.h>
#include <float.h>
#include <math.h>

// Problem constants: query (8,512,64,64) f32, keys (2000,512) f32
constexpr int D_  = 512;
constexpr int HW_ = 4096;           // 64*64
constexpr int N_  = 32768;          // B*HW
constexpr int M_  = 2000;
constexpr int MP_ = 2048;           // padded key count

typedef _Float16 half8 __attribute__((ext_vector_type(8)));
typedef float    f32x4 __attribute__((ext_vector_type(4)));

// ---------------- kernel 1: fused per-pixel rnorm + fp16 A-fragment swizzle ----------------
// qsw holds NORMALIZED q-hat (score downstream: s = kn - 2*acc; rnorm applied ONCE, here).
// qsw[pb][kb][lane][j]: lane L holds A[m = pb*16 + (L&15)][k = kb*32 + (L>>4)*8 + j]
__global__ __launch_bounds__(256) void k_prep(const float* __restrict__ q,
                                              float* __restrict__ rnorm,
                                              _Float16* __restrict__ qsw) {
    __shared__ float  tile[64][65];
    __shared__ float4 part2[16][17];
    __shared__ float  rns[64];
    int t = threadIdx.x;
    int p0 = blockIdx.x * 64;                    // 64 | 4096 -> single batch per block
    const float* base = q + (size_t)(p0 / HW_) * (D_ * HW_) + (p0 % HW_);

    // pass 1: sum of squares, float4-vectorized along hw (4 pixels per thread-lane)
    int px4 = t & 15, cgi = t >> 4;              // 16 pixel-quads x 16 c-groups of 32
    {
        const float* bb = base + px4 * 4;
        float s0 = 0.f, s1 = 0.f, s2 = 0.f, s3 = 0.f;
        for (int c = cgi * 32; c < cgi * 32 + 32; ++c) {
            float4 v = *(const float4*)(bb + (size_t)c * HW_);
            s0 += v.x * v.x; s1 += v.y * v.y; s2 += v.z * v.z; s3 += v.w * v.w;
        }
        part2[px4][cgi] = make_float4(s0, s1, s2, s3);
    }
    __syncthreads();
    if (t < 64) {
        float ss = 0.f;
#pragma unroll
        for (int g = 0; g < 16; ++g)
            ss += ((const float*)&part2[t >> 2][g])[t & 3];
        float rv = 1.0f / fmaxf(sqrtf(ss), 1e-12f);   // matches F.normalize eps
        rns[t] = rv;
        rnorm[p0 + t] = rv;
    }

    // pass 2: re-read (L2-hot), normalize, emit fragment-ordered fp16
    int pb0 = blockIdx.x * 4;
    for (int ct = 0; ct < 8; ++ct) {
        __syncthreads();                         // tile free + rns ready
#pragma unroll
        for (int i = 0; i < 4; ++i) {
            int sl = t + 256 * i;                // 1024 float4 slots: 64 ch-rows x 16
            int row = sl >> 4, p4 = (sl & 15) * 4;
            float4 v = *(const float4*)(base + (size_t)(ct * 64 + row) * HW_ + p4);
            tile[row][p4 + 0] = v.x; tile[row][p4 + 1] = v.y;
            tile[row][p4 + 2] = v.z; tile[row][p4 + 3] = v.w;
        }
        __syncthreads();
#pragma unroll
        for (int i = 0; i < 2; ++i) {
            int f = t + 256 * i;                 // 512 fragments: 8 tiles x 64 lanes
            int ti = f >> 6, L = f & 63;
            int pbi = ti & 3, kbi = ti >> 2;
            int plx = pbi * 16 + (L & 15);
            int cl = kbi * 32 + ((L >> 4) * 8);
            float rv = rns[plx];
            half8 hv;
#pragma unroll
            for (int j = 0; j < 8; ++j) hv[j] = (_Float16)(tile[cl + j][plx] * rv);
            size_t off = (((size_t)(pb0 + pbi) * 16 + (ct * 2 + kbi)) * 64 + L) * 8;
            *(half8*)(qsw + off) = hv;
        }
    }
}

// ---------------- kernel 2: |k|^2 (FLT_MAX for padding) ----------------
__global__ __launch_bounds__(256) void k_kn(const float* __restrict__ keys,
                                            float* __restrict__ kn) {
    int wave = threadIdx.x >> 6;
    int lane = threadIdx.x & 63;
    int m = blockIdx.x * 4 + wave;
    float s = 0.f;
    if (m < M_) {
        const float4* row = (const float4*)(keys + (size_t)m * D_);
        for (int j = lane; j < D_ / 4; j += 64) {
            float4 v = row[j];
            s += v.x * v.x + v.y * v.y + v.z * v.z + v.w * v.w;
        }
    }
    for (int off = 32; off; off >>= 1) s += __shfl_down(s, off, 64);
    if (lane == 0) kn[m] = (m < M_) ? s : FLT_MAX;
}

// ---------------- kernel 3: keys -> fp16, MFMA B-fragment order ----------------
// ksw[nb][kb][lane][j]: lane L holds B[k][n=nb*16+(L&15)] = keys[n][kb*32+(L>>4)*8+j]
__global__ __launch_bounds__(256) void k_ksw(const float* __restrict__ keys,
                                             _Float16* __restrict__ ksw) {
    int f = blockIdx.x * 256 + threadIdx.x;      // 131072 fragments
    int nb = f >> 10, rest = f & 1023;
    int kb = rest >> 6, L = rest & 63;
    int m = nb * 16 + (L & 15);
    int c = kb * 32 + ((L >> 4) * 8);
    half8 hv;
    if (m < M_) {
        float4 v0 = *(const float4*)(keys + (size_t)m * D_ + c);
        float4 v1 = *(const float4*)(keys + (size_t)m * D_ + c + 4);
        hv[0] = (_Float16)v0.x; hv[1] = (_Float16)v0.y;
        hv[2] = (_Float16)v0.z; hv[3] = (_Float16)v0.w;
        hv[4] = (_Float16)v1.x; hv[5] = (_Float16)v1.y;
        hv[6] = (_Float16)v1.z; hv[7] = (_Float16)v1.w;
    } else {
#pragma unroll
        for (int j = 0; j < 8; ++j) hv[j] = (_Float16)0.f;
    }
    *(half8*)(ksw + (size_t)f * 8) = hv;
}

// merge top-2 list (t1,j1,t2,j2) into (s1,i1,s2,i2); both sorted; idx tie-break.
__device__ inline void merge2(float& s1, unsigned& i1, float& s2, unsigned& i2,
                              float t1, unsigned j1, float t2, unsigned j2) {
    if (t1 < s1 || (t1 == s1 && j1 < i1)) {
        float os = s1; unsigned oi = i1;
        s1 = t1; i1 = j1;
        if (os < t2 || (os == t2 && oi < j2)) { s2 = os; i2 = oi; }
        else { s2 = t2; i2 = j2; }
    } else {
        if (t1 < s2 || (t1 == s2 && j1 < i2)) { s2 = t1; i2 = j1; }
    }
}

// ---------------- kernel 4: barrier-free MFMA score GEMM (direct global->VGPR frags) ----------------
// qsw/ksw are fragment-ordered, so each lane's 16B frag is a direct dwordx4 load —
// no LDS staging, no __syncthreads in the K-loop. Depth-1 register prefetch (cur/nxt).
// grid (N/128, 2); 4 waves in 2x2; 128 px x 1024 keys per block = 8 chunks of 128,
// flattened g = ch*16 + dc (128 steps). Score s = kn - 2*acc > 0 -> float bits compare
// as unsigned; pack 5-bit local key id (ch*4+ni) into low mantissa: running top-2 =
// 3 int min/max per score. Trunc 32 ulp ~2e-3 ~ fp16 GEMM noise; both absorbed by
// k_heat's exact fp32 rescue. NOTE (R6 bug): acc must be reset only AFTER the full
// (pi,r,ni) fold — resetting inside the r-loop silently dropped all ni==0 scores
// for r>=1 (missing candidates -> absmax 188).
__global__ __launch_bounds__(256) void k_mfma(const _Float16* __restrict__ qsw,
                                              const _Float16* __restrict__ ksw,
                                              const float* __restrict__ kn,
                                              float4* __restrict__ best) {
    __shared__ float  kns[1024];
    __shared__ float4 red[256];
    int t = threadIdx.x;
    int lane = t & 63;
    int w = __builtin_amdgcn_readfirstlane(t >> 6);
    int wr = w >> 1, wc = w & 1;
    int colk = lane & 15, quad = lane >> 4;
    int p0 = blockIdx.x * 128;
    int yb = blockIdx.y;                         // key half: yb*1024
    int pb0 = p0 >> 4;

    // stage this block's kn range into LDS (keeps the K-loop free of scalar VMEM waits)
#pragma unroll
    for (int i = 0; i < 4; ++i) kns[t + 256 * i] = kn[yb * 1024 + t + 256 * i];
    __syncthreads();

    // fragment base pointers (lane-resolved). A(pi,dc) = aq + pi*8192 + dc*512
    // B(ni,ch,dc) = bk + ch*65536 + ni*8192 + dc*512     (units: _Float16)
    const _Float16* aq = qsw + (size_t)(pb0 + wr * 4) * (16 * 512) + lane * 8;
    const _Float16* bk = ksw + (size_t)(yb * 64 + wc * 4) * (16 * 512) + lane * 8;

    unsigned pk1[16], pk2[16];
#pragma unroll
    for (int i = 0; i < 16; ++i) { pk1[i] = 0xFFFFFFFFu; pk2[i] = 0xFFFFFFFFu; }

    f32x4 acc[4][4];
#pragma unroll
    for (int pi = 0; pi < 4; ++pi)
#pragma unroll
        for (int ni = 0; ni < 4; ++ni) acc[pi][ni] = (f32x4){0.f, 0.f, 0.f, 0.f};

    half8 cur[8], nxt[8];
#pragma unroll
    for (int pi = 0; pi < 4; ++pi) cur[pi] = *(const half8*)(aq + pi * 8192);
#pragma unroll
    for (int ni = 0; ni < 4; ++ni) cur[4 + ni] = *(const half8*)(bk + ni * 8192);

#pragma unroll 2
    for (int g = 0; g < 128; ++g) {
        // prefetch step g+1 while computing step g
        if (g < 127) {
            int g1 = g + 1;
            int dc = g1 & 15, ch = g1 >> 4;
#pragma unroll
            for (int pi = 0; pi < 4; ++pi)
                nxt[pi] = *(const half8*)(aq + pi * 8192 + dc * 512);
#pragma unroll
            for (int ni = 0; ni < 4; ++ni)
                nxt[4 + ni] = *(const half8*)(bk + ch * 65536 + ni * 8192 + dc * 512);
        }
#pragma unroll
        for (int pi = 0; pi < 4; ++pi)
#pragma unroll
            for (int ni = 0; ni < 4; ++ni)
                acc[pi][ni] = __builtin_amdgcn_mfma_f32_16x16x32_f16(
                    cur[pi], cur[4 + ni], acc[pi][ni], 0, 0, 0);

        if ((g & 15) == 15) {                    // chunk complete: fold ALL scores...
            int ch = g >> 4;
            float kc[4];
#pragma unroll
            for (int ni = 0; ni < 4; ++ni) kc[ni] = kns[ch * 128 + wc * 64 + ni * 16 + colk];
#pragma unroll
            for (int pi = 0; pi < 4; ++pi) {
#pragma unroll
                for (int r = 0; r < 4; ++r) {
                    int si = pi * 4 + r;
#pragma unroll
                    for (int ni = 0; ni < 4; ++ni) {
                        float sc = fmaf(-2.0f, acc[pi][ni][r], kc[ni]);
                        unsigned p = (__float_as_uint(sc) & ~31u) | (unsigned)(ch * 4 + ni);
                        unsigned hi = pk1[si] > p ? pk1[si] : p;   // max
                        pk1[si] = pk1[si] < p ? pk1[si] : p;       // min
                        pk2[si] = pk2[si] < hi ? pk2[si] : hi;     // min
                    }
                }
            }
            // ...then reset accumulators (AFTER the fold — R6 bug was resetting inside)
#pragma unroll
            for (int pi = 0; pi < 4; ++pi)
#pragma unroll
                for (int ni = 0; ni < 4; ++ni)
                    acc[pi][ni] = (f32x4){0.f, 0.f, 0.f, 0.f};
        }
#pragma unroll
        for (int i = 0; i < 8; ++i) cur[i] = nxt[i];
    }

    // ---- once-per-block epilogue: unpack, butterfly over 16 colk lanes, LDS wc-merge ----
    __syncthreads();
#pragma unroll
    for (int pi = 0; pi < 4; ++pi) {
#pragma unroll
        for (int r = 0; r < 4; ++r) {
            int si = pi * 4 + r;
            int pix = wr * 64 + pi * 16 + quad * 4 + r;   // C/D: row = quad*4 + reg
            unsigned P1 = pk1[si], P2 = pk2[si];
            float s1 = __uint_as_float(P1 & ~31u);
            float s2 = __uint_as_float(P2 & ~31u);
            unsigned l1 = P1 & 31u, l2 = P2 & 31u;
            unsigned i1 = (unsigned)(yb * 1024) + (l1 >> 2) * 128 + wc * 64 + (l1 & 3) * 16 + colk;
            unsigned i2 = (unsigned)(yb * 1024) + (l2 >> 2) * 128 + wc * 64 + (l2 & 3) * 16 + colk;
#pragma unroll
            for (int mask = 1; mask < 16; mask <<= 1) {
                float t1 = __shfl_xor(s1, mask, 64);
                float t2 = __shfl_xor(s2, mask, 64);
                unsigned j1 = (unsigned)__shfl_xor((int)i1, mask, 64);
                unsigned j2 = (unsigned)__shfl_xor((int)i2, mask, 64);
                merge2(s1, i1, s2, i2, t1, j1, t2, j2);
            }
            if (colk == 0)
                red[pix * 2 + wc] = make_float4(s1, __uint_as_float(i1),
                                                s2, __uint_as_float(i2));
        }
    }
    __syncthreads();
    if (t < 128) {
        float4 e0 = red[t * 2 + 0];
        float4 e1 = red[t * 2 + 1];
        float s1 = e0.x, s2 = e0.z;
        unsigned i1 = __float_as_uint(e0.y), i2 = __float_as_uint(e0.w);
        merge2(s1, i1, s2, i2, e1.x, __float_as_uint(e1.y), e1.z, __float_as_uint(e1.w));
        best[(size_t)yb * N_ + p0 + t] =
            make_float4(s1, __uint_as_float(i1), s2, __uint_as_float(i2));
    }
}

// ---------------- kernel 5: merge 2 halves -> top-2, exact fp32 rescue + heatmap ----------------
// Block = 64 pixels x 4 c-groups (256 thr); 512 blocks.
__global__ __launch_bounds__(256) void k_heat(
    const float* __restrict__ q, const float* __restrict__ keys,
    const float* __restrict__ kn, const float* __restrict__ rnorm,
    const float4* __restrict__ best, float* __restrict__ out)
{
    __shared__ float4 part[64][5];               // (dot0,dot1,hh0,hh1) x 4 cg, +1 pad
    int t = threadIdx.x;
    int pl = t & 63, cg = t >> 6;
    int p0 = blockIdx.x * 64;
    int p = p0 + pl;
    const float* qb = q + (size_t)(p / HW_) * (D_ * HW_) + (p % HW_);

    // merge the 2 per-half top-2 lists (redundantly in each cg thread)
    float4 e0 = best[p];
    float4 e1 = best[N_ + p];
    float s1 = e0.x, s2 = e0.z;
    unsigned i1 = __float_as_uint(e0.y), i2 = __float_as_uint(e0.w);
    merge2(s1, i1, s2, i2, e1.x, __float_as_uint(e1.y), e1.z, __float_as_uint(e1.w));

    float rn = rnorm[p];
    const float* kp0 = keys + (size_t)i1 * D_;
    const float* kp1 = keys + (size_t)i2 * D_;
    float dot0 = 0.f, dot1 = 0.f, hh0 = 0.f, hh1 = 0.f;
    for (int c = cg * 128; c < cg * 128 + 128; c += 4) {
        float qv[4];
#pragma unroll
        for (int j = 0; j < 4; ++j) qv[j] = qb[(size_t)(c + j) * HW_] * rn;  // coalesced
        float4 kv0 = *(const float4*)(kp0 + c);
        float4 kv1 = *(const float4*)(kp1 + c);
        dot0 += qv[0] * kv0.x + qv[1] * kv0.y + qv[2] * kv0.z + qv[3] * kv0.w;
        dot1 += qv[0] * kv1.x + qv[1] * kv1.y + qv[2] * kv1.z + qv[3] * kv1.w;
        float a0 = qv[0] - kv0.x, a1 = qv[1] - kv0.y, a2 = qv[2] - kv0.z, a3 = qv[3] - kv0.w;
        float b0 = qv[0] - kv1.x, b1 = qv[1] - kv1.y, b2 = qv[2] - kv1.z, b3 = qv[3] - kv1.w;
        float A0 = a0 * a0, A1 = a1 * a1, A2 = a2 * a2, A3 = a3 * a3;
        float B0 = b0 * b0, B1 = b1 * b1, B2 = b2 * b2, B3 = b3 * b3;
        hh0 += A0 * A0 + A1 * A1 + A2 * A2 + A3 * A3;
        hh1 += B0 * B0 + B1 * B1 + B2 * B2 + B3 * B3;
    }
    part[pl][cg] = make_float4(dot0, dot1, hh0, hh1);
    __syncthreads();
    if (t < 64) {                                // cg==0 thread for pixel t holds i1,i2
        float4 a = part[t][0], b = part[t][1], c4 = part[t][2], d = part[t][3];
        float dA = a.x + b.x + c4.x + d.x;
        float dB = a.y + b.y + c4.y + d.y;
        float hA = a.z + b.z + c4.z + d.z;
        float hB = a.w + b.w + c4.w + d.w;
        float sA = kn[i1] - 2.0f * dA;
        float sB = kn[i2] - 2.0f * dB;
        // argmin semantics: smaller exact score wins; tie -> smaller index
        bool takeB = (sB < sA) || (sB == sA && i2 < i1);
        out[p0 + t] = takeB ? hB : hA;
    }
}

extern "C" void kernel_launch(void* const* d_in, const int* in_sizes, int n_in,
                              void* d_out, int out_size, void* d_ws, size_t ws_size,
                              hipStream_t stream) {
    const float* query = (const float*)d_in[0];   // (8,512,64,64) f32
    const float* keys  = (const float*)d_in[1];   // (2000,512) f32
    float* out = (float*)d_out;                   // 32768 f32

    // workspace layout (~37 MB):
    char* ws = (char*)d_ws;
    _Float16* qsw   = (_Float16*)ws;                                 // N*D fp16  = 33.5 MB
    _Float16* ksw   = (_Float16*)(ws + (size_t)N_ * D_ * 2);         // MP*D fp16 = 2 MB
    float*    rnorm = (float*)(ws + (size_t)N_ * D_ * 2 + (size_t)MP_ * D_ * 2);
    float*    kn    = rnorm + N_;
    float4*   best  = (float4*)(kn + MP_);                           // 2*N float4 = 1 MB

    k_kn  <<<MP_ / 4,             256, 0, stream>>>(keys, kn);
    k_ksw <<<MP_ * D_ / 8 / 256,  256, 0, stream>>>(keys, ksw);
    k_prep<<<N_ / 64,             256, 0, stream>>>(query, rnorm, qsw);
    k_mfma<<<dim3(N_ / 128, 2),   256, 0, stream>>>(qsw, ksw, kn, best);
    k_heat<<<N_ / 64,             256, 0, stream>>>(query, keys, kn, rnorm, best, out);
}